// Round 7
// baseline (445.995 us; speedup 1.0000x reference)
//
#include <hip/hip_runtime.h>
#include <cstdint>
#include <cstddef>

constexpr int T_ = 128;
constexpr int S_ = 512;
constexpr int B_ = 256;
constexpr int START_ = T_ - 3;  // 125
constexpr int STOP_  = T_ - 2;  // 126

// Barrier that only drains LDS (lgkmcnt), NOT vmcnt: global bp-stores and
// e-prefetch loads legally stay in flight across it (thread-private data).
__device__ __forceinline__ void lds_barrier() {
  asm volatile("s_waitcnt lgkmcnt(0)\n\ts_barrier" ::: "memory");
}

// forced 3-input max (VOP3). Inputs are finite (no NaN in this problem):
// v_max3_f32(a,b,c) == fmaxf(fmaxf(a,b),c) bit-exactly.
__device__ __forceinline__ float max3f(float a, float b, float c) {
  float d;
  asm("v_max3_f32 %0, %1, %2, %3" : "=v"(d) : "v"(a), "v"(b), "v"(c));
  return d;
}

template <int CTRL>
__device__ __forceinline__ float dppf(float v) {
  return __int_as_float(
      __builtin_amdgcn_mov_dpp(__float_as_int(v), CTRL, 0xF, 0xF, true));
}
template <int CTRL>
__device__ __forceinline__ int dppi(int v) {
  return __builtin_amdgcn_mov_dpp(v, CTRL, 0xF, 0xF, true);
}

// max-reduce over the 8 ig-lanes (lane bits [0,3)): quad xor1 (0xB1),
// quad xor2 (0x4E), row_half_mirror (0x141 == xor4 once quad-uniform).
__device__ __forceinline__ float ig8_rmax(float m) {
  m = fmaxf(m, dppf<0xB1>(m));
  m = fmaxf(m, dppf<0x4E>(m));
  m = fmaxf(m, dppf<0x141>(m));
  return m;
}
// min-reduce (int) over the same 8 ig-lanes.
__device__ __forceinline__ int ig8_rmin_i(int c) {
  c = min(c, dppi<0xB1>(c));
  c = min(c, dppi<0x4E>(c));
  c = min(c, dppi<0x141>(c));
  return c;
}

// padded part layout: value i at float offset i + 4*(i>>4) (R8-proven:
// 8 granule quads disjoint over all 32 banks, broadcast dup free).
__device__ __forceinline__ int pidx(int i) { return i + 4 * (i >> 4); }

// ---------------------------------------------------------------------------
// Forward: Viterbi values + BACKPOINTERS (new in R14). Trace wall-time is
// bound by its serial chain (256 chains already cover 256 CUs; R13 measured
// ~600 cyc/chase-step for the recompute chain). Fix: compute argmax HERE,
// where the 930-cyc barrier skeleton has idle issue slots, and let trace be
// a pure lookup. Exactness: reference argmax is over fl(fl(p+tr)+e) -- e
// included (rounding can create ties) -- so we compare fl(a_i+e) == np
// (np = fl(mm+e) == max_i fl(a_i+e) by monotonicity), descending select
// chain for first-occurrence, cross-lane min of code=16*ig+loc.
// bp layout: u32 at (g*B + b)*128 + j packs slots t=4g..4g+3 (byte t&3),
// where slot t = argmax of forward step t (== reference back_points[t-1]).
// Coalesced u32 stores every 4th step; no LDS staging needed.
// ph is GONE: only bp (16 MB) + lastrow (B,T fp32, written at t==len-1).
// ---------------------------------------------------------------------------
__global__ __launch_bounds__(1024, 4) void viterbi_forward(
    const float* __restrict__ feats,   // (B,S,T)
    const void*  __restrict__ mask,    // (B,S) dtype sniffed
    const float* __restrict__ trans,   // (T,T)
    uint32_t* __restrict__ bp32,       // (S/4,B,T) packed argmax bytes
    float* __restrict__ lastrow)       // (B,T)
{
  const int b    = blockIdx.x;
  const int tid  = threadIdx.x;
  const int lane = tid & 63;
  const int ig   = lane & 7;           // i-chunk: i in [16ig, 16ig+16)
  const int j    = tid >> 3;           // 0..127: this thread's output column

  __shared__ alignas(16) float part[2][160];
  __shared__ int s_len;

  // trans column j, rows 16ig..16ig+16 (16 VGPRs, fixed over t)
  float tc[16];
  #pragma unroll
  for (int ii = 0; ii < 16; ++ii)
    tc[ii] = trans[(16 * ig + ii) * T_ + j];

  const float* fb = feats + (size_t)b * S_ * T_;
  const int woff  = pidx(j);
  const int basev = ig << 4;

  // sequence length (wave 0; dtype: uint8 / float32 / int32)
  if (tid < 64) {
    int l = 0;
    const int w0 = *(const int*)mask;  // element (0,0) is always true
    if (w0 == 0x01010101) {
      const unsigned char* m = (const unsigned char*)mask + (size_t)b * S_;
      for (int s = tid; s < S_; s += 64) l += (m[s] != 0);
    } else if (w0 == 0x3F800000) {
      const float* m = (const float*)mask + (size_t)b * S_;
      for (int s = tid; s < S_; s += 64) l += (m[s] != 0.0f);
    } else {
      const int* m = (const int*)mask + (size_t)b * S_;
      for (int s = tid; s < S_; s += 64) l += (m[s] != 0);
    }
    #pragma unroll
    for (int o = 32; o > 0; o >>= 1) l += __shfl_xor(l, o);
    if (tid == 0) s_len = l;
  }

  // t = 0: part0 = emit[0] + trans[START,:]  (slot 0 of bp stays 0: pk init)
  float p00 = fb[j] + trans[START_ * T_ + j];
  if (ig == 0) part[0][woff] = p00;
  __syncthreads();
  const int lenm1 = s_len - 1;

  uint32_t* bpw = bp32 + (size_t)b * T_ + j;    // + g*(B_*T_) per flush
  float*    lrw = lastrow + (size_t)b * T_ + j;
  unsigned  pk  = 0;

  auto stepf = [&](int t, float e, int sh, bool flsh) {
    const float4* p4 = (const float4*)part[(t - 1) & 1];
    float4 pa = p4[5 * ig];
    float4 pb = p4[5 * ig + 1];
    float4 pc = p4[5 * ig + 2];
    float4 pd = p4[5 * ig + 3];
    float a0  = pa.x + tc[0],  a1  = pa.y + tc[1],
          a2  = pa.z + tc[2],  a3  = pa.w + tc[3];
    float a4  = pb.x + tc[4],  a5  = pb.y + tc[5],
          a6  = pb.z + tc[6],  a7  = pb.w + tc[7];
    float a8  = pc.x + tc[8],  a9  = pc.y + tc[9],
          a10 = pc.z + tc[10], a11 = pc.w + tc[11];
    float a12 = pd.x + tc[12], a13 = pd.y + tc[13],
          a14 = pd.z + tc[14], a15 = pd.w + tc[15];
    float x0 = max3f(a0, a1, a2);
    float x1 = max3f(a3, a4, a5);
    float x2 = max3f(a6, a7, a8);
    float x3 = max3f(a9, a10, a11);
    float x4 = max3f(a12, a13, a14);
    float y0 = max3f(x0, x1, x2);
    float y1 = max3f(x3, x4, a15);
    float mm = ig8_rmax(fmaxf(y0, y1));  // all 8 ig-lanes hold max over i
    float np = mm + e;
    if (ig == 0) part[t & 1][woff] = np;

    // ---- first-occurrence argmax over i of fl(a_i + e) == np ----
    // descending so lower i overwrites: first-match wins (matches jnp.argmax)
    int loc = 255;
    loc = ((a15 + e) == np) ? 15 : loc;
    loc = ((a14 + e) == np) ? 14 : loc;
    loc = ((a13 + e) == np) ? 13 : loc;
    loc = ((a12 + e) == np) ? 12 : loc;
    loc = ((a11 + e) == np) ? 11 : loc;
    loc = ((a10 + e) == np) ? 10 : loc;
    loc = ((a9  + e) == np) ?  9 : loc;
    loc = ((a8  + e) == np) ?  8 : loc;
    loc = ((a7  + e) == np) ?  7 : loc;
    loc = ((a6  + e) == np) ?  6 : loc;
    loc = ((a5  + e) == np) ?  5 : loc;
    loc = ((a4  + e) == np) ?  4 : loc;
    loc = ((a3  + e) == np) ?  3 : loc;
    loc = ((a2  + e) == np) ?  2 : loc;
    loc = ((a1  + e) == np) ?  1 : loc;
    loc = ((a0  + e) == np) ?  0 : loc;
    int code = basev + loc;              // no-match lanes: >= 255 (sentinel)
    code = ig8_rmin_i(code);             // global first-occurrence index
    pk |= (unsigned)code << (8 * sh);    // byte slot t&3

    lds_barrier();
    if (flsh) {
      if (ig == 0) bpw[(size_t)(t >> 2) * (B_ * T_)] = pk;  // coalesced u32
      pk = 0;
    }
    if (t == lenm1 && ig == 0) *lrw = np;
  };

  // emission prefetch: 8 rows in flight (named A/B groups of 4, no rotation)
  float EA[4], EB[4];
  #pragma unroll
  for (int u = 0; u < 4; ++u)
    EA[u] = fb[(size_t)(1 + u) * T_ + j];

  for (int t0 = 1; t0 < S_; t0 += 8) {
    #pragma unroll
    for (int u = 0; u < 4; ++u) {
      int tr = t0 + 4 + u; if (tr > S_ - 1) tr = S_ - 1;
      EB[u] = fb[(size_t)tr * T_ + j];
    }
    #pragma unroll
    for (int u = 0; u < 4; ++u) {
      int t = t0 + u;                    // t&3 = (1+u)&3 since t0 % 8 == 1
      if (t < S_) stepf(t, EA[u], (1 + u) & 3, u == 2);
    }
    #pragma unroll
    for (int u = 0; u < 4; ++u) {
      int tr = t0 + 8 + u; if (tr > S_ - 1) tr = S_ - 1;
      EA[u] = fb[(size_t)tr * T_ + j];
    }
    #pragma unroll
    for (int u = 0; u < 4; ++u) {
      int t = t0 + 4 + u;                // t&3 = (5+u)&3 = (1+u)&3
      if (t < S_) stepf(t, EB[u], (1 + u) & 3, u == 2);
    }
  }
}

// ---------------------------------------------------------------------------
// Trace (R14 rewrite): pure bp-lookup chase -- no recompute, no transT, no
// feats. Chain per step: 2 readlane + select + byte-extract (~25-40 cyc vs
// R13's ~600). bp groups (4 slots each) prefetched 8 groups (32 steps)
// ahead, double-buffered. rev[k] = slot(k+1)[carry]; out packed per group.
// ---------------------------------------------------------------------------
__global__ __launch_bounds__(64, 1) void viterbi_trace(
    const void*  __restrict__ mask,     // (B,S) dtype sniffed
    const float* __restrict__ trans,    // (T,T)
    const uint32_t* __restrict__ bp32,  // (S/4,B,T) packed
    const float* __restrict__ lastrow,  // (B,T)
    int* __restrict__ out)              // (B,S) int32
{
  const int b    = blockIdx.x;
  const int lane = threadIdx.x;

  // ---- sequence length ----
  int len = 0;
  {
    const int w0 = *(const int*)mask;
    if (w0 == 0x01010101) {
      const unsigned char* m = (const unsigned char*)mask + (size_t)b * S_;
      for (int s = lane; s < S_; s += 64) len += (m[s] != 0);
    } else if (w0 == 0x3F800000) {
      const float* m = (const float*)mask + (size_t)b * S_;
      for (int s = lane; s < S_; s += 64) len += (m[s] != 0.0f);
    } else {
      const int* m = (const int*)mask + (size_t)b * S_;
      for (int s = lane; s < S_; s += 64) len += (m[s] != 0);
    }
    #pragma unroll
    for (int o = 32; o > 0; o >>= 1) len += __shfl_xor(len, o);
  }
  const int lp = len - 1;               // last valid position (>= S/2-1)

  // ---- final pointer: first argmax_i(lastrow[i] + trans[i][STOP]) ----
  const float2 L = *(const float2*)(lastrow + (size_t)b * T_ + 2 * lane);
  const float tc0 = trans[(2 * lane) * T_ + STOP_];
  const float tc1 = trans[(2 * lane + 1) * T_ + STOP_];
  float v0 = L.x + tc0;
  float v1 = L.y + tc1;
  float mx = fmaxf(v0, v1);
  #pragma unroll
  for (int o = 32; o > 0; o >>= 1) mx = fmaxf(mx, __shfl_xor(mx, o));
  unsigned long long g0 = __ballot(v0 == mx);
  unsigned long long g1 = __ballot(v1 == mx);
  int p0 = g0 ? 2 * (__ffsll(g0) - 1)     : (1 << 30);
  int p1 = g1 ? 2 * (__ffsll(g1) - 1) + 1 : (1 << 30);
  const int pointer = min(p0, p1);

  // ---- masked tail: out[k]=0 for lp<k<S-1; out[S-1]=out[lp]=pointer ----
  for (int k = lp + 1 + lane; k <= S_ - 2; k += 64) out[b * S_ + k] = 0;
  if (lane == 0) {
    out[b * S_ + (S_ - 1)] = pointer;
    if (lp < S_ - 1) out[b * S_ + lp] = pointer;
  }

  // ---- chase: for s = lp..1: ptr = slot_s[ptr]; out[s-1] = ptr ----
  int ptr = pointer;
  const uint32_t* bpb = bp32 + (size_t)b * T_;  // group g at + g*(B_*T_)

  uint2 GA[8], GB[8];
  auto issueG = [&](uint2 (&G)[8], int gb) {
    #pragma unroll
    for (int u = 0; u < 8; ++u) {
      int g = gb - u; if (g < 0) g = 0;        // clamped slots never used
      G[u] = *(const uint2*)(bpb + (size_t)g * (B_ * T_) + 2 * lane);
    }
  };
  auto processG = [&](const uint2 (&G)[8], int gb) {
    #pragma unroll
    for (int u = 0; u < 8; ++u) {
      const int g = gb - u;
      if (g >= 0) {
        unsigned pk = 0;
        int cnt = 0;
        #pragma unroll
        for (int q = 3; q >= 0; --q) {
          const int s = 4 * g + q;
          if (s >= 1 && s <= lp) {
            int x = __builtin_amdgcn_readlane((int)G[u].x, ptr >> 1);
            int y = __builtin_amdgcn_readlane((int)G[u].y, ptr >> 1);
            int v = (ptr & 1) ? y : x;
            ptr = (v >> (8 * q)) & 0xff;
            pk = (pk << 8) | (unsigned)ptr;    // LSB ends at smallest s
            ++cnt;
          }
        }
        if (cnt > 0) {
          int smin = 4 * g; if (smin < 1) smin = 1;
          if (lane < cnt)
            out[b * S_ + (smin - 1) + lane] = (int)((pk >> (8 * lane)) & 0xffu);
        }
      }
    }
  };

  const int G0 = lp >> 2;
  issueG(GA, G0);
  for (int gb = G0; gb >= 0; gb -= 16) {
    issueG(GB, gb - 8);
    processG(GA, gb);
    issueG(GA, gb - 16);
    processG(GB, gb - 8);
  }
}

extern "C" void kernel_launch(void* const* d_in, const int* in_sizes, int n_in,
                              void* d_out, int out_size, void* d_ws, size_t ws_size,
                              hipStream_t stream) {
  const float* feats = (const float*)d_in[0];   // (B,S,T) fp32
  const void*  mask  = d_in[1];                 // (B,S) bool-ish
  const float* trans = (const float*)d_in[2];   // (T,T) fp32
  uint32_t* bp32     = (uint32_t*)d_ws;         // 16 MB packed backpointers
  float*    lastrow  = (float*)((char*)d_ws + (size_t)16 * 1024 * 1024);
  int*      out      = (int*)d_out;             // (B,S) int32

  viterbi_forward<<<dim3(B_), dim3(1024), 0, stream>>>(feats, mask, trans,
                                                       bp32, lastrow);
  viterbi_trace  <<<dim3(B_), dim3(64),   0, stream>>>(mask, trans, bp32,
                                                       lastrow, out);
}

// Round 8
// 325.847 us; speedup vs baseline: 1.3687x; 1.3687x over previous
//
#include <hip/hip_runtime.h>
#include <cstdint>
#include <cstddef>

constexpr int T_ = 128;
constexpr int S_ = 512;
constexpr int B_ = 256;
constexpr int START_ = T_ - 3;  // 125
constexpr int STOP_  = T_ - 2;  // 126

// Barrier that only drains LDS (lgkmcnt), NOT vmcnt: global ph-stores and
// e-prefetch loads legally stay in flight across it (thread-private data).
__device__ __forceinline__ void lds_barrier() {
  asm volatile("s_waitcnt lgkmcnt(0)\n\ts_barrier" ::: "memory");
}

// readlane: wave-uniform lane index (SGPR) -> ~VALU-speed broadcast.
__device__ __forceinline__ float readlane_f(float v, int sl) {
  return __int_as_float(__builtin_amdgcn_readlane(__float_as_int(v), sl));
}

// forced 3-input max (VOP3). Inputs are finite (no NaN in this problem):
// v_max3_f32(a,b,c) == fmaxf(fmaxf(a,b),c) bit-exactly.
__device__ __forceinline__ float max3f(float a, float b, float c) {
  float d;
  asm("v_max3_f32 %0, %1, %2, %3" : "=v"(d) : "v"(a), "v"(b), "v"(c));
  return d;
}

// max-reduce over the 8 ig-lanes (lane bits [0,3)) in pure row-DPP:
// quad xor1 (0xB1), quad xor2 (0x4E), row_half_mirror (0x141: reverses each
// 8-lane half; == xor4 once quad-uniform). All 8 lanes end with the max.
__device__ __forceinline__ float ig8_rmax(float m) {
  int x = __builtin_amdgcn_mov_dpp(__float_as_int(m), 0xB1, 0xF, 0xF, true);
  m = fmaxf(m, __int_as_float(x));
  x = __builtin_amdgcn_mov_dpp(__float_as_int(m), 0x4E, 0xF, 0xF, true);
  m = fmaxf(m, __int_as_float(x));
  x = __builtin_amdgcn_mov_dpp(__float_as_int(m), 0x141, 0xF, 0xF, true);
  m = fmaxf(m, __int_as_float(x));
  return m;
}

// padded part layout: value i at float offset i + 4*(i>>4).
// Thread ig's 16-float granule = floats [20ig, 20ig+16) (byte 80ig, 16B
// aligned). Quad-banks 20ig%32 = {0,20,8,28,16,4,24,12}+0..3: the 8 granule
// quads are disjoint and cover all 32 banks -> conflict-free; 8-fold
// same-address lane duplication is LDS broadcast (free).
__device__ __forceinline__ int pidx(int i) { return i + 4 * (i >> 4); }

// ---------------------------------------------------------------------------
// Forward: value-only Viterbi recursion, stores part_hist (S,B,T) fp32.
// R15: revert to the measured-best R8/R13 structure verbatim (203 us, 930
// cyc/step = ~660 issue + ~270 write/barrier/read skeleton). R14's inline
// argmax (+60 instrs/thread/step) nearly doubled issue -> 358 us; there is
// no idle-slot slack. This round's experiment lives in viterbi_trace.
// Bit-exact vs reference: max exactly associative, fl monotone =>
// max_i fl(fl(p+tr)+e) == fl(max_i fl(p+tr) + e).
// ---------------------------------------------------------------------------
__global__ __launch_bounds__(1024, 4) void viterbi_forward(
    const float* __restrict__ feats,   // (B,S,T)
    const float* __restrict__ trans,   // (T,T)
    float* __restrict__ ph)            // (S,B,T) workspace
{
  const int b    = blockIdx.x;
  const int tid  = threadIdx.x;
  const int lane = tid & 63;
  const int ig   = lane & 7;           // i-chunk: i in [16ig, 16ig+16)
  const int j    = tid >> 3;           // 0..127: this thread's output column

  __shared__ alignas(16) float part[2][160];

  // trans column j, rows 16ig..16ig+16 (16 VGPRs, fixed over t)
  float tc[16];
  #pragma unroll
  for (int ii = 0; ii < 16; ++ii)
    tc[ii] = trans[(16 * ig + ii) * T_ + j];

  const float* fb = feats + (size_t)b * S_ * T_;
  const int woff  = pidx(j);

  // t = 0: part0 = emit[0] + trans[START,:]
  float p0 = fb[j] + trans[START_ * T_ + j];
  if (ig == 0) {
    part[0][woff] = p0;
    ph[(size_t)b * T_ + j] = p0;
  }
  __syncthreads();

  auto stepf = [&](int t, float e) {
    const float4* p4 = (const float4*)part[(t - 1) & 1];
    float4 pa = p4[5 * ig];
    float4 pb = p4[5 * ig + 1];
    float4 pc = p4[5 * ig + 2];
    float4 pd = p4[5 * ig + 3];
    float a0  = pa.x + tc[0],  a1  = pa.y + tc[1],
          a2  = pa.z + tc[2],  a3  = pa.w + tc[3];
    float a4  = pb.x + tc[4],  a5  = pb.y + tc[5],
          a6  = pb.z + tc[6],  a7  = pb.w + tc[7];
    float a8  = pc.x + tc[8],  a9  = pc.y + tc[9],
          a10 = pc.z + tc[10], a11 = pc.w + tc[11];
    float a12 = pd.x + tc[12], a13 = pd.y + tc[13],
          a14 = pd.z + tc[14], a15 = pd.w + tc[15];
    float x0 = max3f(a0, a1, a2);
    float x1 = max3f(a3, a4, a5);
    float x2 = max3f(a6, a7, a8);
    float x3 = max3f(a9, a10, a11);
    float x4 = max3f(a12, a13, a14);
    float y0 = max3f(x0, x1, x2);
    float y1 = max3f(x3, x4, a15);
    float mm = fmaxf(y0, y1);
    mm = ig8_rmax(mm);                 // all 8 ig-lanes now hold max over i
    float np = mm + e;
    if (ig == 0) part[t & 1][woff] = np;
    lds_barrier();
    if (ig == 0)
      ph[((size_t)t * B_ + b) * T_ + j] = np;  // off critical path
  };

  // emission prefetch: 8 rows in flight (named A/B groups of 4, no rotation)
  float EA[4], EB[4];
  #pragma unroll
  for (int u = 0; u < 4; ++u)
    EA[u] = fb[(size_t)(1 + u) * T_ + j];

  for (int t0 = 1; t0 < S_; t0 += 8) {
    #pragma unroll
    for (int u = 0; u < 4; ++u) {
      int tr = t0 + 4 + u; if (tr > S_ - 1) tr = S_ - 1;
      EB[u] = fb[(size_t)tr * T_ + j];
    }
    #pragma unroll
    for (int u = 0; u < 4; ++u) { int t = t0 + u; if (t < S_) stepf(t, EA[u]); }
    #pragma unroll
    for (int u = 0; u < 4; ++u) {
      int tr = t0 + 8 + u; if (tr > S_ - 1) tr = S_ - 1;
      EA[u] = fb[(size_t)tr * T_ + j];
    }
    #pragma unroll
    for (int u = 0; u < 4; ++u) { int t = t0 + 4 + u; if (t < S_) stepf(t, EB[u]); }
  }
}

// ---------------------------------------------------------------------------
// Trace: one wave per b, grid 256. R15 CHANGE: SCALARIZE ptr. R13/R14 both
// ran 10-20x over the modeled chain latency (600 vs ~50 cyc/step). Cause:
// ptr flows from __ffsll/min on ballot results -> lives in VGPRs -> every
// readlane(x, ptr>>1) has a divergent index -> compiler emits a waterfall
// loop (save-exec/readfirstlane/cmp/branch) around EACH one, several per
// step, all on the serial chain. ptr is mathematically wave-uniform, so
// one readfirstlane per update makes every downstream readlane / select /
// address scalar. Structure otherwise identical to R13 (packed u64 store
// flush, pipelined trc ds_read, 8-deep double-buffered prefetch).
// Semantics unchanged: bit-exact first-occurrence argmax via equality
// ballots on identically-rounded candidates.
// ---------------------------------------------------------------------------
constexpr int CH_ = 8;   // chunk size (steps per buffer)
constexpr int TS_ = 130; // transT row stride (even: float2-aligned, 2-way ok)

__global__ __launch_bounds__(64, 1) void viterbi_trace(
    const float* __restrict__ feats,   // (B,S,T)
    const void*  __restrict__ mask,    // (B,S) dtype detected at runtime
    const float* __restrict__ trans,   // (T,T)
    const float* __restrict__ ph,      // (S,B,T)
    int* __restrict__ out)             // (B,S) int32
{
  const int b    = blockIdx.x;
  const int lane = threadIdx.x;

  __shared__ alignas(16) float transT[T_ * TS_];  // transT[j*TS+i] = trans[i][j]
  #pragma unroll 4
  for (int g = lane; g < T_ * T_; g += 64) {
    int i = g >> 7, jj = g & (T_ - 1);
    transT[jj * TS_ + i] = trans[g];
  }
  __syncthreads();

  // ---- sequence length (mask dtype: uint8 / float32 / int32) ----
  int len = 0;
  {
    const int w0 = *(const int*)mask;  // element (0,0) is always true
    if (w0 == 0x01010101) {
      const unsigned char* m = (const unsigned char*)mask + (size_t)b * S_;
      for (int s = lane; s < S_; s += 64) len += (m[s] != 0);
    } else if (w0 == 0x3F800000) {
      const float* m = (const float*)mask + (size_t)b * S_;
      for (int s = lane; s < S_; s += 64) len += (m[s] != 0.0f);
    } else {
      const int* m = (const int*)mask + (size_t)b * S_;
      for (int s = lane; s < S_; s += 64) len += (m[s] != 0);
    }
    #pragma unroll
    for (int o = 32; o > 0; o >>= 1) len += __shfl_xor(len, o);
  }
  // scalarize: len is uniform -> scalar loop bounds / addressing downstream
  len = __builtin_amdgcn_readfirstlane(len);
  const int lp = len - 1;              // last valid position (>= S/2-1)

  // ---- final pointer: first argmax_i(ph_lp[i] + trans[i][STOP]) ----
  const float2 L = *(const float2*)(ph + ((size_t)lp * B_ + b) * T_ + 2 * lane);
  float v0 = L.x + transT[STOP_ * TS_ + 2 * lane];
  float v1 = L.y + transT[STOP_ * TS_ + 2 * lane + 1];
  float mx = fmaxf(v0, v1);
  #pragma unroll
  for (int o = 32; o > 0; o >>= 1) mx = fmaxf(mx, __shfl_xor(mx, o));
  {
    unsigned long long g0 = __ballot(v0 == mx);
    unsigned long long g1 = __ballot(v1 == mx);
    int p0 = g0 ? 2 * (__ffsll(g0) - 1)     : (1 << 30);
    int p1 = g1 ? 2 * (__ffsll(g1) - 1) + 1 : (1 << 30);
    int pointer = __builtin_amdgcn_readfirstlane(min(p0, p1));  // scalar

    // ---- masked tail: out[k]=0 for lp<k<S-1; out[S-1]=out[lp]=pointer ----
    for (int k = lp + 1 + lane; k <= S_ - 2; k += 64) out[b * S_ + k] = 0;
    if (lane == 0) {
      out[b * S_ + (S_ - 1)] = pointer;
      if (lp < S_ - 1) out[b * S_ + lp] = pointer;
    }

    // ---- chase k = lp-1 .. 0 ----
    int   ptr = pointer;                                      // SGPR-resident
    float tg  = readlane_f((ptr & 1) ? L.y : L.x, ptr >> 1);  // ph[lp][ptr]
    const float* fb = feats + (size_t)b * S_ * T_;
    const float2 FL = *(const float2*)(fb + (size_t)lp * T_ + 2 * lane);
    float e = readlane_f((ptr & 1) ? FL.y : FL.x, ptr >> 1);  // feats[lp][ptr]
    // pipelined transT row for the first chase step
    float2 trc = *(const float2*)(transT + ptr * TS_ + 2 * lane);

    float2 PA[CH_], FA[CH_], PB[CH_], FB[CH_];

    auto issue = [&](float2 (&P)[CH_], float2 (&F)[CH_], int k0) {
      #pragma unroll
      for (int s = 0; s < CH_; ++s) {
        int k = k0 - s; if (k < 0) k = 0;     // clamped slots never used
        P[s] = *(const float2*)(ph + ((size_t)k * B_ + b) * T_ + 2 * lane);
        F[s] = *(const float2*)(fb + (size_t)k * T_ + 2 * lane);
      }
    };
    auto process = [&](const float2 (&P)[CH_], const float2 (&F)[CH_], int k0) {
      unsigned long long packed = 0;
      int cnt = 0;
      #pragma unroll
      for (int s = 0; s < CH_; ++s) {
        const int k = k0 - s;
        if (k >= 0) {
          // candidates c_i = fl(fl(ph_k[i]+trans[i,ptr]) + e), i = 2l, 2l+1
          float cx = (P[s].x + trc.x) + e;
          float cy = (P[s].y + trc.y) + e;
          unsigned long long q0 = __ballot(cx == tg);
          unsigned long long q1 = __ballot(cy == tg);
          int a0 = q0 ? 2 * (__ffsll(q0) - 1)     : (1 << 30);
          int a1 = q1 ? 2 * (__ffsll(q1) - 1) + 1 : (1 << 30);
          ptr = __builtin_amdgcn_readfirstlane(min(a0, a1));  // kill waterfalls
          // issue next transT row ASAP; latency hides under the rest
          trc = *(const float2*)(transT + ptr * TS_ + 2 * lane);
          // accumulate instead of storing (store off the chain)
          packed = (packed << 8) | (unsigned)ptr;
          ++cnt;
          // next step (k-1) targets ph_k[ptr], feats[k][ptr]
          tg = readlane_f((ptr & 1) ? P[s].y : P[s].x, ptr >> 1);
          e  = readlane_f((ptr & 1) ? F[s].y : F[s].x, ptr >> 1);
        }
      }
      // flush: step s handled k = k0-s; its ptr is byte (cnt-1-s) of packed
      if (lane < cnt)
        out[b * S_ + (k0 - lane)] =
            (int)((packed >> (8 * (cnt - 1 - lane))) & 0xFFull);
    };

    issue(PA, FA, lp - 1);
    for (int k0 = lp - 1; k0 >= 0; k0 -= 2 * CH_) {
      issue(PB, FB, k0 - CH_);
      process(PA, FA, k0);
      issue(PA, FA, k0 - 2 * CH_);
      process(PB, FB, k0 - CH_);
    }
  }
}

extern "C" void kernel_launch(void* const* d_in, const int* in_sizes, int n_in,
                              void* d_out, int out_size, void* d_ws, size_t ws_size,
                              hipStream_t stream) {
  const float* feats = (const float*)d_in[0];   // (B,S,T) fp32
  const void*  mask  = d_in[1];                 // (B,S) bool-ish
  const float* trans = (const float*)d_in[2];   // (T,T) fp32
  float* ph = (float*)d_ws;                     // (S,B,T) fp32 = 64 MB
  int*   out = (int*)d_out;                     // (B,S) int32

  viterbi_forward<<<dim3(B_), dim3(1024), 0, stream>>>(feats, trans, ph);
  viterbi_trace  <<<dim3(B_), dim3(64), 0, stream>>>(feats, mask, trans, ph, out);
}